// Round 1
// baseline (150.664 us; speedup 1.0000x reference)
//
#include <hip/hip_runtime.h>

// y[e, o] = sum_i weight[widx[e]][o][i] * values[iidx[e]][i]
// E = 1e6, N_W = 1024, D_IN = D_OUT = 16, fp32.
//
// History: R1 naive 137us (latency-bound: scattered W loads, no batching).
// R2 global-atomic scatter 203us. R3-R9 bucket sort + per-bucket mv; mv
// 58-70us. R10 deep-MLP mv: 46us mv, but TOTAL 146us -> the 4-kernel sort
// (~100us: hist/scan/scan/scatter + 16MB perm traffic) dominates.
//
// R11 theory: W is only 1MB -> L2-resident in every XCD. The sort exists
// only to make W wave-uniform; skip it entirely and pay W from L2 per conn:
//   floor = max(L2: 1e6 x 1KB = 1GB @ 34.5TB/s ~ 30us,
//               HBM: ~136MB @ 6.3TB/s ~ 22us,
//               VALU: ~770 instr/batch -> ~400cy/batch/CU)  => L2-bound ~32us.
// Structure (R10 playbook applied to W, fixing R1's latency failure):
//   - one wave/block, 64-conn batches, BPB batches/block
//   - x: R10 gather (4 instrs -> 64 random lines in flight), XOR-swizzled
//     wave-local LDS, no barriers; 1-deep cross-batch pipeline
//   - W: ONE coalesced 1KB instr per conn (lane l -> row l>>2 quarter l&3),
//     groups of 8 conns double-buffered -> 8-16 loads always in flight
//   - compute: per-lane dot4, reduce across quad via 2x shfl_xor (DPP),
//     lanes q==0 store y[r] (16x4B dwords, one 64B line)
// Predicted: 1 dispatch, ~55-75us total, FETCH ~65MB, WRITE ~64MB,
// VALUBusy 40-55%. Failure mode: >100us + VALUBusy<20% => latency-bound,
// revert to sort+mv hybrid.

#define D 16
#define BPB 4   // 64-conn batches per block (256 conns, mirrors R10 segments)

__device__ __forceinline__ float4 wload(const float* __restrict__ weight,
                                        int wi, int lane) {
    // whole 16x16 matrix in one instr: 64 lanes x 16B = 1KB contiguous
    return ((const float4*)(weight + (long long)wi * (D * D)))[lane];
}

#define WLOAD8(C0, W0,W1,W2,W3,W4,W5,W6,W7) do {                               \
    W0 = wload(weight, __builtin_amdgcn_readlane(wcur, (C0)+0), lane);         \
    W1 = wload(weight, __builtin_amdgcn_readlane(wcur, (C0)+1), lane);         \
    W2 = wload(weight, __builtin_amdgcn_readlane(wcur, (C0)+2), lane);         \
    W3 = wload(weight, __builtin_amdgcn_readlane(wcur, (C0)+3), lane);         \
    W4 = wload(weight, __builtin_amdgcn_readlane(wcur, (C0)+4), lane);         \
    W5 = wload(weight, __builtin_amdgcn_readlane(wcur, (C0)+5), lane);         \
    W6 = wload(weight, __builtin_amdgcn_readlane(wcur, (C0)+6), lane);         \
    W7 = wload(weight, __builtin_amdgcn_readlane(wcur, (C0)+7), lane);         \
} while (0)

// lane l holds W[wi][r][4q..4q+3] (r=l>>2, q=l&3); x quarter q of conn C sits
// at swizzled slot q^(C>>4). Partial dot4, then sum the 4 quad lanes.
#define CONN1(C, WV) do {                                                      \
    const float4 xv = *(const float4*)(&xbuf[(C) * D + ((q ^ ((C) >> 4)) << 2)]); \
    float p = WV.x*xv.x + WV.y*xv.y + WV.z*xv.z + WV.w*xv.w;                   \
    p += __shfl_xor(p, 1);                                                     \
    p += __shfl_xor(p, 2);                                                     \
    if (q == 0 && (C) < nb) out[(long long)(k0 + (C)) * D + r] = p;            \
} while (0)

#define CONN8(C0, W0,W1,W2,W3,W4,W5,W6,W7) do {                                \
    CONN1((C0)+0, W0); CONN1((C0)+1, W1); CONN1((C0)+2, W2); CONN1((C0)+3, W3);\
    CONN1((C0)+4, W4); CONN1((C0)+5, W5); CONN1((C0)+6, W6); CONN1((C0)+7, W7);\
} while (0)

__global__ __launch_bounds__(64, 4) void direct_mv(
    const float* __restrict__ values, const float* __restrict__ weight,
    const int* __restrict__ iidx, const int* __restrict__ widx,
    float* __restrict__ out, int E)
{
    __shared__ float xbuf[64 * D];   // 4KB, wave-local, no barriers
    const int lane = threadIdx.x;    // 0..63
    const int g4 = lane >> 2;        // gather: conn-in-16 (0..15); compute: row r
    const int q  = lane & 3;         // quarter (0..3)
    const int r  = g4;

    int s0 = blockIdx.x * (64 * BPB);
    if (s0 >= E) return;
    int s1 = min(E, s0 + 64 * BPB);

    // ---- prologue: gather batch @ s0 into registers ----
    int iv, wnext;                   // iidx/widx of conn s0+lane (clamped)
    float4 xq0, xq1, xq2, xq3;       // quarter q of conns {u*16+g4}
    {
        int kl = s0 + lane; if (kl >= s1) kl = s1 - 1;
        iv    = iidx[kl];
        wnext = widx[kl];
        int iiu;
        iiu = __shfl(iv,      g4); xq0 = ((const float4*)(values + (long long)iiu * D))[q];
        iiu = __shfl(iv, 16 + g4); xq1 = ((const float4*)(values + (long long)iiu * D))[q];
        iiu = __shfl(iv, 32 + g4); xq2 = ((const float4*)(values + (long long)iiu * D))[q];
        iiu = __shfl(iv, 48 + g4); xq3 = ((const float4*)(values + (long long)iiu * D))[q];
    }

    for (int k0 = s0; k0 < s1; k0 += 64) {
        // commit current batch x to LDS (XOR-swizzled quarter slots)
        ((float4*)&xbuf[( 0 + g4) * D])[q ^ 0] = xq0;
        ((float4*)&xbuf[(16 + g4) * D])[q ^ 1] = xq1;
        ((float4*)&xbuf[(32 + g4) * D])[q ^ 2] = xq2;
        ((float4*)&xbuf[(48 + g4) * D])[q ^ 3] = xq3;
        int wcur = wnext;
        int nb = s1 - k0; if (nb > 64) nb = 64;

        // prefetch next batch (idx + 64 x-lines) while computing this one
        int kn = k0 + 64;
        if (kn < s1) {
            int kl = kn + lane; if (kl >= s1) kl = s1 - 1;
            iv    = iidx[kl];
            wnext = widx[kl];
            int iiu;
            iiu = __shfl(iv,      g4); xq0 = ((const float4*)(values + (long long)iiu * D))[q];
            iiu = __shfl(iv, 16 + g4); xq1 = ((const float4*)(values + (long long)iiu * D))[q];
            iiu = __shfl(iv, 32 + g4); xq2 = ((const float4*)(values + (long long)iiu * D))[q];
            iiu = __shfl(iv, 48 + g4); xq3 = ((const float4*)(values + (long long)iiu * D))[q];
        }

        // compute: 8 groups of 8 conns, W loads double-buffered so the next
        // group's 8 coalesced 1KB loads are in flight during current compute
        float4 A0,A1,A2,A3,A4,A5,A6,A7;
        float4 B0,B1,B2,B3,B4,B5,B6,B7;
        WLOAD8( 0, A0,A1,A2,A3,A4,A5,A6,A7);
        WLOAD8( 8, B0,B1,B2,B3,B4,B5,B6,B7);
        CONN8 ( 0, A0,A1,A2,A3,A4,A5,A6,A7);
        WLOAD8(16, A0,A1,A2,A3,A4,A5,A6,A7);
        CONN8 ( 8, B0,B1,B2,B3,B4,B5,B6,B7);
        WLOAD8(24, B0,B1,B2,B3,B4,B5,B6,B7);
        CONN8 (16, A0,A1,A2,A3,A4,A5,A6,A7);
        WLOAD8(32, A0,A1,A2,A3,A4,A5,A6,A7);
        CONN8 (24, B0,B1,B2,B3,B4,B5,B6,B7);
        WLOAD8(40, B0,B1,B2,B3,B4,B5,B6,B7);
        CONN8 (32, A0,A1,A2,A3,A4,A5,A6,A7);
        WLOAD8(48, A0,A1,A2,A3,A4,A5,A6,A7);
        CONN8 (40, B0,B1,B2,B3,B4,B5,B6,B7);
        WLOAD8(56, B0,B1,B2,B3,B4,B5,B6,B7);
        CONN8 (48, A0,A1,A2,A3,A4,A5,A6,A7);
        CONN8 (56, B0,B1,B2,B3,B4,B5,B6,B7);
    }
}

extern "C" void kernel_launch(void* const* d_in, const int* in_sizes, int n_in,
                              void* d_out, int out_size, void* d_ws, size_t ws_size,
                              hipStream_t stream) {
    const float* values     = (const float*)d_in[0];
    const float* weight     = (const float*)d_in[1];
    const int*   input_idx  = (const int*)d_in[2];
    const int*   weight_idx = (const int*)d_in[3];
    float*       out        = (float*)d_out;

    int E = in_sizes[2];
    if (E <= 0) return;
    int nblk = (E + 64 * BPB - 1) / (64 * BPB);
    hipLaunchKernelGGL(direct_mv, dim3(nblk), dim3(64), 0, stream,
                       values, weight, input_idx, weight_idx, out, E);
}